// Round 8
// baseline (8076.872 us; speedup 1.0000x reference)
//
#include <hip/hip_runtime.h>
#include <hip/hip_bf16.h>
#include <stdint.h>
#include <stddef.h>

// ---- problem constants ----
#define NB 8
#define TT 256
#define IDIM 256
#define HH 512
#define VV 256
#define DD 32
#define NDEC 64
#define NTHINK 16
#define HCB 8
#define HSL 64
#define NTHR 1024

// ---- ws layout (bytes), 8B aligned ----
#define HEX_OFF 0u        // [2][NB][HH]  u64 = 65,536
#define YEX_OFF 65536u    // [2][NB][HCB][VV] u64 = 262,144
#define FEX_OFF 327680u   // [NTHINK][NB] u64 = 1,024
#define DLY_OFF 328704u   // 512*512 u8 = 262,144 -> end 590,848
#define EXZ_BYTES 328704u // memset span (hex+yex+fex)

// ---------------- stamped exchange: (stamp<<32 | f32bits), fence-free ------
__device__ __forceinline__ void pubf(uint64_t* p, float v, uint32_t stamp){
  const uint64_t pk = ((uint64_t)stamp << 32) | (uint64_t)__float_as_uint(v);
  __hip_atomic_store(p, pk, __ATOMIC_RELAXED, __HIP_MEMORY_SCOPE_AGENT);
}
__device__ __forceinline__ float waitf(uint64_t* p, uint32_t stamp){
  uint64_t pk;
  do { pk = __hip_atomic_load(p, __ATOMIC_RELAXED, __HIP_MEMORY_SCOPE_AGENT); }
  while ((uint32_t)(pk >> 32) != stamp);
  return __uint_as_float((uint32_t)pk);
}

// ---------------- threefry2x32 (matches jax) ----------------
__device__ __forceinline__ void tfr(uint32_t &x0, uint32_t &x1, int r){
  x0 += x1; x1 = (x1 << r) | (x1 >> (32 - r)); x1 ^= x0;
}
__device__ __forceinline__ void threefry(uint32_t k0, uint32_t k1,
                                         uint32_t c0, uint32_t c1,
                                         uint32_t &o0, uint32_t &o1){
  const uint32_t k2 = k0 ^ k1 ^ 0x1BD11BDAu;
  uint32_t x0 = c0 + k0, x1 = c1 + k1;
  tfr(x0,x1,13); tfr(x0,x1,15); tfr(x0,x1,26); tfr(x0,x1,6);
  x0 += k1; x1 += k2 + 1u;
  tfr(x0,x1,17); tfr(x0,x1,29); tfr(x0,x1,16); tfr(x0,x1,24);
  x0 += k2; x1 += k0 + 2u;
  tfr(x0,x1,13); tfr(x0,x1,15); tfr(x0,x1,26); tfr(x0,x1,6);
  x0 += k0; x1 += k1 + 3u;
  tfr(x0,x1,17); tfr(x0,x1,29); tfr(x0,x1,16); tfr(x0,x1,24);
  x0 += k1; x1 += k2 + 4u;
  tfr(x0,x1,13); tfr(x0,x1,15); tfr(x0,x1,26); tfr(x0,x1,6);
  x0 += k2; x1 += k0 + 5u;
  o0 = x0; o1 = x1;
}
// jax partitionable threefry random_bits (32-bit): counter (0, i), bits = o0^o1
__device__ __forceinline__ uint32_t pbits(uint32_t k0, uint32_t k1, uint32_t i){
  uint32_t o0, o1; threefry(k0, k1, 0u, i, o0, o1);
  return o0 ^ o1;
}
__device__ __forceinline__ float bits_to_unit(uint32_t bits){
  return __uint_as_float((bits >> 9) | 0x3F800000u) - 1.0f;
}

// ---------------- kernel A: credit argmax -> delay table (0 = dead) --------
__global__ __launch_bounds__(256) void delays_kernel(
    const float* __restrict__ tau, unsigned char* __restrict__ dl)
{
  const int e = blockIdx.x * 256 + threadIdx.x;
  if (e >= HH*HH) return;
  uint32_t kc0, kc1; threefry(0u, 42u, 0u, 0u, kc0, kc1);  // fold_in(key(42),0)
  const float tcf = fminf(fmaxf(tau[e], 1.0f), 32.0f);
  const double tc = (double)tcf;
  double best = -1.0e300; int am = 0;
  for (int d = 0; d <= DD; ++d){
    const uint32_t f = (uint32_t)d * (uint32_t)(HH*HH) + (uint32_t)e;
    const double u = (double)bits_to_unit(pbits(kc0, kc1, f));
    const double raw = 1.0 / sqrt(1.0 + fabs((double)d - tc));
    const double pert = log(raw + 1e-8) - log(-log(u + 1e-8) + 1e-8);
    if (pert > best){ best = pert; am = d; }
  }
  dl[e] = (unsigned char)am;
}

// ---------------- kernel B: the sequential RNN -------------
__global__ __launch_bounds__(NTHR) void seq_kernel(
    const float* __restrict__ x, const int* __restrict__ lengths,
    const float* __restrict__ aff_w, const float* __restrict__ aff_b,
    const float* __restrict__ eff_w, const float* __restrict__ eff_b,
    const float* __restrict__ lateral, const unsigned char* __restrict__ dl,
    uint64_t* __restrict__ hex_, uint64_t* __restrict__ yex,
    uint64_t* __restrict__ fex, float* __restrict__ out)
{
  extern __shared__ double smd[];
  double* curr  = smd;                      // 256
  double* lastv = curr + 256;               // 256
  double* ypq   = lastv + 256;              // 1024
  double* hdels = ypq + 1024;               // 64
  double* redv  = hdels + 64;               // 4
  float*  hist  = (float*)(redv + 4);       // 32*513
  float*  effs  = hist + 32*513;            // 64*256
  float*  effbs = effs + 64*256;            // 256
  float*  ypl   = effbs + 256;              // 2048
  int*    redi  = (int*)(ypl + 2048);       // 4
  int*    misc  = redi + 4;                 // 16

  const int tid = threadIdx.x;
  const int b   = blockIdx.x & 7;
  const int hc  = blockIdx.x >> 3;
  const int hl  = tid >> 4;                 // local h 0..63
  const int p   = tid & 15;                 // 16 lanes per h
  const int h   = hc * HSL + hl;

  // persistent regs: w split by delay class; delays packed; aff_w col slice
  float w_old[32], w1[32]; uint32_t dpk[8]; float aw[16];
  #pragma unroll
  for (int k = 0; k < 32; ++k){
    const int idx = h*HH + p + 16*k;
    const int d = (int)dl[idx];
    const float wv = (d >= 1) ? lateral[idx] : 0.0f;
    w1[k]    = (d == 1) ? wv : 0.0f;
    w_old[k] = (d == 1) ? 0.0f : wv;
    dpk[k >> 2] = (k & 3) ? (dpk[k >> 2] | ((uint32_t)d << ((k & 3)*8)))
                          : (uint32_t)d;
  }
  #pragma unroll
  for (int m = 0; m < 16; ++m) aw[m] = aff_w[(p + 16*m)*HH + h];
  const double ab = (double)aff_b[h];

  for (int q = tid; q < 32*513; q += NTHR) hist[q] = 0.0f;
  for (int q = tid; q < HSL*VV; q += NTHR) effs[q] = eff_w[hc*HSL*VV + q];
  if (tid < VV) effbs[tid] = eff_b[tid];
  __syncthreads();

  const int L = lengths[b];
  uint32_t st = 0;   // completed h-exchange rounds (round r carries h(r-1))

  // d>=2 partial, rows (st-d)&31 — d==1 terms masked to 0 (benign race row)
  auto aold = [&](double &a0){
    const int tm = (int)(st & 31u);
    a0 = 0.0;
    #pragma unroll
    for (int k = 0; k < 32; ++k){
      const int d = (int)((dpk[k >> 2] >> ((k & 3)*8)) & 0xFFu);
      const int row = (tm - d) & 31;
      a0 += (double)w_old[k] * (double)hist[row*513 + p + 16*k];
    }
  };
  auto anew_reduce = [&](double &a0, double &a1){
    const int rn = (int)((st + 31u) & 31u);   // row of h(st-1)
    #pragma unroll
    for (int k = 0; k < 32; ++k)
      a0 += (double)w1[k] * (double)hist[rn*513 + p + 16*k];
    #pragma unroll
    for (int m = 1; m < 16; m <<= 1){
      a0 += __shfl_xor(a0, m, 64);
      a1 += __shfl_xor(a1, m, 64);
    }
  };
  auto ypartial = [&](){
    const int q = tid >> 8, v = tid & 255;
    double acc = 0.0;
    #pragma unroll
    for (int m = 0; m < 16; ++m)
      acc += hdels[q*16 + m] * (double)effs[(q*16 + m)*VV + v];
    ypq[q*256 + v] = acc;
  };
  auto argmax256 = [&](double pr){
    if (tid < VV){
      double bv = pr; int bi = tid;
      #pragma unroll
      for (int m = 1; m < 64; m <<= 1){
        const double ov = __shfl_xor(bv, m, 64);
        const int    oi = __shfl_xor(bi, m, 64);
        if (ov > bv || (ov == bv && oi < bi)){ bv = ov; bi = oi; }
      }
      if ((tid & 63) == 0){ redv[tid >> 6] = bv; redi[tid >> 6] = bi; }
    }
    __syncthreads();
    if (tid == 0){
      double bv = redv[0]; int bi = redi[0];
      #pragma unroll
      for (int q2 = 1; q2 < 4; ++q2)
        if (redv[q2] > bv || (redv[q2] == bv && redi[q2] < bi)){ bv = redv[q2]; bi = redi[q2]; }
      misc[0] = bi;
    }
    __syncthreads();
  };
  auto gumbel_t = [&](uint32_t base, int sv) -> double {
    uint32_t k0, k1; threefry(0u, 42u, 0u, base + (uint32_t)sv, k0, k1);
    const uint32_t f = (uint32_t)(b*VV + tid);
    float u = bits_to_unit(pbits(k0, k1, f));
    if (u < 1.1754944e-38f) u = 1.1754944e-38f;
    return log(-log((double)u));
  };

  // ================= ENCODER (1 sync + 1 exchange per step) =================
  for (; st < (uint32_t)L; ){
    double a0, a1 = 0.0;
    aold(a0);
    {
      const float* xr = x + ((size_t)b*TT + st)*IDIM + p;
      #pragma unroll
      for (int m = 0; m < 16; ++m) a1 += (double)aw[m] * (double)xr[16*m];
    }
    // wait round st (h(st-1)); memset stamp0 serves h(-1)=0
    uint64_t* slabR = hex_ + ((st & 1u)*NB + b)*HH;
    if (tid < HH) hist[(int)((st + 31u) & 31u)*513 + tid] = waitf(slabR + tid, st);
    __syncthreads();
    anew_reduce(a0, a1);
    const double hn = tanh(a0 + a1 + ab);
    if (p == 0) pubf(hex_ + (((st + 1u) & 1u)*NB + b)*HH + h, (float)hn, st + 1u);
    ++st;
  }

  // ================= THINK =================
  if (tid < IDIM){
    const double xv = (double)x[((size_t)b*TT + (L-1))*IDIM + tid];
    curr[tid] = xv; lastv[tid] = xv;
  }
  __syncthreads();

  bool done = false; int tst = 0;
  for (int s = 0; s < NTHINK; ++s){
    double a0, a1 = 0.0;
    aold(a0);
    #pragma unroll
    for (int m = 0; m < 16; ++m) a1 += (double)aw[m] * curr[p + 16*m];
    if (hc == 0 && tid == 0)
      __hip_atomic_store(fex + s*NB + b, (uint64_t)(done ? 2u : 1u),
                         __ATOMIC_RELAXED, __HIP_MEMORY_SCOPE_AGENT);
    uint64_t* slabR = hex_ + ((st & 1u)*NB + b)*HH;
    if (tid < HH){
      hist[(int)((st + 31u) & 31u)*513 + tid] = waitf(slabR + tid, st);
    } else if (tid < HH + NB){
      uint64_t v;
      do { v = __hip_atomic_load(fex + s*NB + (tid - HH), __ATOMIC_RELAXED,
                                 __HIP_MEMORY_SCOPE_AGENT); } while (v == 0ull);
      misc[2 + (tid - HH)] = (v == 2ull);
    }
    __syncthreads();
    {
      int ad = 1;
      #pragma unroll
      for (int bb = 0; bb < NB; ++bb) ad &= misc[2 + bb];
      if (ad) break;                 // freeze: consumed but nothing published
    }
    anew_reduce(a0, a1);
    const double hn = tanh(a0 + a1 + ab);
    const uint32_t sw = st + 1u;
    const int parW = (int)(sw & 1u);
    if (p == 0){ pubf(hex_ + (parW*NB + b)*HH + h, (float)hn, sw); hdels[hl] = a0; }
    __syncthreads();
    ypartial();
    __syncthreads();
    uint64_t* ybase = yex + ((size_t)(parW*NB + b)*HCB)*VV;
    if (tid < VV)
      pubf(ybase + hc*VV + tid,
           (float)(ypq[tid] + ypq[256 + tid] + ypq[512 + tid] + ypq[768 + tid]), sw);
    ypl[tid]        = waitf(ybase + tid, sw);
    ypl[tid + 1024] = waitf(ybase + tid + 1024, sw);
    __syncthreads();
    double yv = 0.0, pr = 0.0;
    if (tid < VV){
      double acc = (double)effbs[tid];
      #pragma unroll
      for (int c = 0; c < HCB; ++c) acc += (double)ypl[c*VV + tid];
      yv = acc;
      pr = yv - gumbel_t(1000u, s);
    }
    argmax256(pr);
    const int sampled = misc[0];
    const bool just = (sampled == VV - 1) && !done;
    if (!done){
      ++tst;
      if (tid < VV) lastv[tid] = yv;
    }
    const bool nd = done || just;
    if (tid < VV) curr[tid] = nd ? 0.0 : yv;
    done = nd;
    ++st;
    __syncthreads();
  }

  // ================= DECODE =================
  if (tid < VV) curr[tid] = lastv[tid];
  __syncthreads();
  for (int dj = 0; dj < NDEC; ++dj){
    double a0, a1 = 0.0;
    aold(a0);
    #pragma unroll
    for (int m = 0; m < 16; ++m) a1 += (double)aw[m] * curr[p + 16*m];
    uint64_t* slabR = hex_ + ((st & 1u)*NB + b)*HH;
    if (tid < HH) hist[(int)((st + 31u) & 31u)*513 + tid] = waitf(slabR + tid, st);
    __syncthreads();
    anew_reduce(a0, a1);
    const double hn = tanh(a0 + a1 + ab);
    const uint32_t sw = st + 1u;
    const int parW = (int)(sw & 1u);
    if (p == 0){ pubf(hex_ + (parW*NB + b)*HH + h, (float)hn, sw); hdels[hl] = a0; }
    __syncthreads();
    ypartial();
    __syncthreads();
    uint64_t* ybase = yex + ((size_t)(parW*NB + b)*HCB)*VV;
    if (tid < VV)
      pubf(ybase + hc*VV + tid,
           (float)(ypq[tid] + ypq[256 + tid] + ypq[512 + tid] + ypq[768 + tid]), sw);
    ypl[tid]        = waitf(ybase + tid, sw);
    ypl[tid + 1024] = waitf(ybase + tid + 1024, sw);
    __syncthreads();
    double yv = 0.0, pr = 0.0;
    if (tid < VV){
      double acc = (double)effbs[tid];
      #pragma unroll
      for (int c = 0; c < HCB; ++c) acc += (double)ypl[c*VV + tid];
      yv = acc;
      if (hc == 0 && tid < VV - 1)
        out[((size_t)b*NDEC + dj)*(VV - 1) + tid] = (float)yv;   // raw logits
      pr = yv - gumbel_t(2000u, dj);
    }
    argmax256(pr);
    const int sampled = misc[0];
    if (tid < VV) curr[tid] = (tid == sampled) ? 1.0 : 0.0;  // straight-through
    ++st;
    __syncthreads();
  }
  if (hc == 0 && tid == 0) out[NB*NDEC*(VV-1) + b] = (float)tst;
}

// ---------------- launcher ----------------
extern "C" void kernel_launch(void* const* d_in, const int* in_sizes, int n_in,
                              void* d_out, int out_size, void* d_ws, size_t ws_size,
                              hipStream_t stream)
{
  (void)in_sizes; (void)n_in; (void)out_size; (void)ws_size;
  const float* x     = (const float*)d_in[0];
  const int*   len   = (const int*)  d_in[1];
  const float* affw  = (const float*)d_in[2];
  const float* affb  = (const float*)d_in[3];
  const float* later = (const float*)d_in[4];
  const float* effw  = (const float*)d_in[5];
  const float* effb  = (const float*)d_in[6];
  const float* tau   = (const float*)d_in[7];

  char* ws = (char*)d_ws;
  uint64_t* hex_     = (uint64_t*)(ws + HEX_OFF);
  uint64_t* yex      = (uint64_t*)(ws + YEX_OFF);
  uint64_t* fex      = (uint64_t*)(ws + FEX_OFF);
  unsigned char* dl  = (unsigned char*)(ws + DLY_OFF);

  hipMemsetAsync(ws, 0, EXZ_BYTES, stream);   // reset stamps each launch/replay
  delays_kernel<<<dim3((HH*HH)/256), dim3(256), 0, stream>>>(tau, dl);

  const int smem = (256 + 256 + 1024 + 64 + 4) * 8
                 + (32*513 + 64*256 + 256 + 2048) * 4 + 20 * 4;
  hipFuncSetAttribute((const void*)seq_kernel,
                      hipFuncAttributeMaxDynamicSharedMemorySize, smem);
  seq_kernel<<<dim3(64), dim3(NTHR), smem, stream>>>(
      x, len, affw, affb, effw, effb, later, dl, hex_, yex, fex,
      (float*)d_out);
}